// Round 5
// baseline (332.961 us; speedup 1.0000x reference)
//
#include <hip/hip_runtime.h>
#include <math.h>

#define H_HEADS 33
#define C_CH    16
#define HC      528      // H_HEADS * C_CH
#define F_IN    128
#define NEG_SLOPE 0.2f

typedef short  bf16x8  __attribute__((ext_vector_type(8)));
typedef float  floatx4 __attribute__((ext_vector_type(4)));

__device__ inline unsigned short f2bf(float f) {   // RNE float->bf16
    unsigned int u = __float_as_uint(f);
    unsigned int r = u + 0x7fffu + ((u >> 16) & 1u);
    return (unsigned short)(r >> 16);
}
__device__ inline float bf2f(unsigned short u) {
    return __uint_as_float((unsigned int)u << 16);
}

// ---------------------------------------------------------------------------
// K0a: xb = bf16(x)
// ---------------------------------------------------------------------------
__global__ void cvt_x_kernel(const float* __restrict__ x,
                             unsigned short* __restrict__ xb, int total4)
{
    int g = blockIdx.x * blockDim.x + threadIdx.x;
    if (g >= total4) return;
    float4 v = ((const float4*)x)[g];
    unsigned int lo = (unsigned int)f2bf(v.x) | ((unsigned int)f2bf(v.y) << 16);
    unsigned int hi = (unsigned int)f2bf(v.z) | ((unsigned int)f2bf(v.w) << 16);
    ((uint2*)xb)[g] = make_uint2(lo, hi);
}

// K0b: Wt = bf16(W^T), [528][128]
__global__ void cvt_w_kernel(const float* __restrict__ W,
                             unsigned short* __restrict__ Wt)
{
    int g = blockIdx.x * blockDim.x + threadIdx.x;
    if (g >= F_IN * HC) return;
    int k = g / HC, n = g % HC;
    Wt[n * F_IN + k] = f2bf(W[g]);
}

// ---------------------------------------------------------------------------
// Counting sort of edges by src: hist -> block scan -> wave scan -> scatter.
// Gives perm[] s.t. edges in perm-order have ascending src -> cache-hot
// gathers in denom/aggregate.
// ---------------------------------------------------------------------------
__global__ void hist_kernel(const int* __restrict__ ei, int* __restrict__ cnt,
                            int E, int Et)
{
    int g = blockIdx.x * blockDim.x + threadIdx.x;
    if (g >= Et) return;
    int src = (g < E) ? ei[g] : g - E;
    atomicAdd(&cnt[src], 1);
}

// 1024 elements per block (256 thr x 4), exclusive prefix within block -> ex[],
// block total -> bsum[].
__global__ __launch_bounds__(256) void scan_block_kernel(
    const int* __restrict__ cnt, int* __restrict__ ex,
    int* __restrict__ bsum, int N)
{
    __shared__ int s[256];
    const int t = threadIdx.x;
    const int base = blockIdx.x * 1024 + t * 4;
    int c[4], tot = 0;
    #pragma unroll
    for (int j = 0; j < 4; ++j) {
        c[j] = (base + j < N) ? cnt[base + j] : 0;
        tot += c[j];
    }
    s[t] = tot;
    __syncthreads();
    #pragma unroll
    for (int off = 1; off < 256; off <<= 1) {
        int v = (t >= off) ? s[t - off] : 0;
        __syncthreads();
        s[t] += v;
        __syncthreads();
    }
    if (t == 255) bsum[blockIdx.x] = s[255];
    int run = s[t] - tot;             // exclusive across threads
    #pragma unroll
    for (int j = 0; j < 4; ++j) {
        if (base + j < N) ex[base + j] = run;
        run += c[j];
    }
}

// single wave: bsum[0..nb) -> exclusive offsets in place (nb <= 64)
__global__ void scan_bsum_kernel(int* __restrict__ bsum, int nb)
{
    int lane = threadIdx.x;
    int v = (lane < nb) ? bsum[lane] : 0;
    int inc = v;
    #pragma unroll
    for (int off = 1; off < 64; off <<= 1) {
        int u = __shfl_up(inc, off);
        if (lane >= off) inc += u;
    }
    if (lane < nb) bsum[lane] = inc - v;
}

__global__ void scatter_kernel(const int* __restrict__ ei,
                               const int* __restrict__ bsum,
                               int* __restrict__ ex, int* __restrict__ perm,
                               int E, int Et)
{
    int g = blockIdx.x * blockDim.x + threadIdx.x;
    if (g >= Et) return;
    int src = (g < E) ? ei[g] : g - E;
    int pos = bsum[src >> 10] + atomicAdd(&ex[src], 1);
    perm[pos] = g;
}

// ---------------------------------------------------------------------------
// K1: h_bf16 = xb @ Wt^T via MFMA 16x16x32 bf16. BM=64, BN=48, K=128 in LDS.
// BN=48 == 3 heads -> fused epilogue reduces a_src/a_dst from fp32 acc.
// ---------------------------------------------------------------------------
#define LDA 136
__global__ __launch_bounds__(256) void gemm_att_kernel(
    const unsigned short* __restrict__ xb, const unsigned short* __restrict__ Wt,
    const float* __restrict__ att_src, const float* __restrict__ att_dst,
    unsigned short* __restrict__ hb,
    float* __restrict__ a_src, float* __restrict__ a_dst, int N)
{
    __shared__ unsigned short As[64][LDA];
    __shared__ unsigned short Bs[48][LDA];

    const int tid  = threadIdx.x;
    const int lane = tid & 63;
    const int wave = tid >> 6;
    const int lm   = lane & 15;
    const int kc   = lane >> 4;
    const int m0   = blockIdx.x * 64;
    const int n0   = blockIdx.y * 48;

    for (int e = tid; e < 64 * 16; e += 256) {
        int r = e >> 4, c = e & 15;
        int gr = m0 + r;
        uint4 v = (gr < N) ? ((const uint4*)(xb + (size_t)gr * F_IN))[c]
                           : make_uint4(0, 0, 0, 0);
        *(uint4*)&As[r][c * 8] = v;
    }
    for (int e = tid; e < 48 * 16; e += 256) {
        int r = e >> 4, c = e & 15;
        uint4 v = ((const uint4*)(Wt + (size_t)(n0 + r) * F_IN))[c];
        *(uint4*)&Bs[r][c * 8] = v;
    }
    __syncthreads();

    floatx4 acc[3] = {};
    const int arow = wave * 16 + lm;
    #pragma unroll
    for (int ks = 0; ks < 4; ++ks) {
        bf16x8 a = *(const bf16x8*)&As[arow][ks * 32 + kc * 8];
        #pragma unroll
        for (int t = 0; t < 3; ++t) {
            bf16x8 b = *(const bf16x8*)&Bs[t * 16 + lm][ks * 32 + kc * 8];
            acc[t] = __builtin_amdgcn_mfma_f32_16x16x32_bf16(a, b, acc[t], 0, 0, 0);
        }
    }

    // C/D layout: col = lane&15, row = (lane>>4)*4 + reg
    #pragma unroll
    for (int t = 0; t < 3; ++t) {
        const int head = blockIdx.y * 3 + t;
        const float w_s = att_src[head * C_CH + lm];
        const float w_d = att_dst[head * C_CH + lm];
        #pragma unroll
        for (int r = 0; r < 4; ++r) {
            const int row = m0 + wave * 16 + kc * 4 + r;
            float s = acc[t][r] * w_s;
            float d = acc[t][r] * w_d;
            #pragma unroll
            for (int m = 8; m >= 1; m >>= 1) {
                s += __shfl_xor(s, m);
                d += __shfl_xor(d, m);
            }
            if (row < N) {
                hb[(size_t)row * HC + n0 + t * 16 + lm] = f2bf(acc[t][r]);
                if (lm == 0) {
                    a_src[row * H_HEADS + head] = s;
                    a_dst[row * H_HEADS + head] = d;
                }
            }
        }
    }
}

// ---------------------------------------------------------------------------
// K2: denom[dst,hd] += exp(leakyrelu(...)), edges walked in src-sorted order.
// segment-max skipped: |e| small -> exp() safe; softmax shift-invariant.
// ---------------------------------------------------------------------------
__global__ void denom_kernel(const int* __restrict__ ei,
                             const int* __restrict__ perm,
                             const float* __restrict__ a_src,
                             const float* __restrict__ a_dst,
                             float* __restrict__ denom,
                             int E, int Et)
{
    int g = blockIdx.x * blockDim.x + threadIdx.x;
    if (g >= Et * H_HEADS) return;
    int i = g / H_HEADS, hd = g - i * H_HEADS;
    int e = perm[i];
    int src, dst;
    if (e < E) { src = ei[e]; dst = ei[E + e]; }
    else       { src = dst = e - E; }
    float v = a_src[src * H_HEADS + hd] + a_dst[dst * H_HEADS + hd];
    v = v > 0.f ? v : NEG_SLOPE * v;
    atomicAdd(&denom[dst * H_HEADS + hd], __expf(v));
}

// K2b: denom -> 1/(denom + 1e-16) in place
__global__ void inv_kernel(float* __restrict__ denom, int total)
{
    int g = blockIdx.x * blockDim.x + threadIdx.x;
    if (g >= total) return;
    denom[g] = 1.0f / (denom[g] + 1e-16f);
}

// ---------------------------------------------------------------------------
// K3: 16 edges/block in src-sorted order (hb gathers cache-hot).
// Phase 1: 16x33 alphas once into LDS. Phase 2: lane (edge,c) fma + atomics.
// ---------------------------------------------------------------------------
#define EPB 16
__global__ __launch_bounds__(256) void aggregate_kernel(
    const int* __restrict__ ei, const int* __restrict__ perm,
    const float* __restrict__ a_src, const float* __restrict__ a_dst,
    const float* __restrict__ inv_denom,
    const unsigned short* __restrict__ hb,
    float* __restrict__ out, int E, int Et)
{
    __shared__ int   s_src[EPB], s_dst[EPB];
    __shared__ float s_alpha[EPB][H_HEADS];

    const int tid = threadIdx.x;
    const int e0  = blockIdx.x * EPB;

    if (tid < EPB) {
        int idx = e0 + tid;
        int s = 0, d = 0;
        if (idx < Et) {
            int e = perm[idx];
            if (e < E) { s = ei[e]; d = ei[E + e]; }
            else       { s = d = e - E; }
        }
        s_src[tid] = s;
        s_dst[tid] = d;
    }
    __syncthreads();

    for (int i = tid; i < EPB * H_HEADS; i += 256) {
        int el = i / H_HEADS, hd = i - el * H_HEADS;
        if (e0 + el < Et) {
            int src = s_src[el], dst = s_dst[el];
            float v = a_src[src * H_HEADS + hd] + a_dst[dst * H_HEADS + hd];
            v = v > 0.f ? v : NEG_SLOPE * v;
            s_alpha[el][hd] = __expf(v) * inv_denom[dst * H_HEADS + hd];
        }
    }
    __syncthreads();

    const int el = tid >> 4, c = tid & 15;
    if (e0 + el >= Et) return;
    const int src = s_src[el], dst = s_dst[el];
    const unsigned short* hs = hb + (size_t)src * HC + c;
    float acc = 0.f;
    #pragma unroll
    for (int hd = 0; hd < H_HEADS; ++hd)
        acc += s_alpha[el][hd] * bf2f(hs[hd * C_CH]);
    atomicAdd(&out[dst * C_CH + c], acc);
}

// K4: out = tanh(out/H + bias), in place
__global__ void finalize_kernel(float* __restrict__ out,
                                const float* __restrict__ bias, int total)
{
    int g = blockIdx.x * blockDim.x + threadIdx.x;
    if (g >= total) return;
    out[g] = tanhf(out[g] * (1.0f / 33.0f) + bias[g & 15]);
}

// ---------------------------------------------------------------------------
extern "C" void kernel_launch(void* const* d_in, const int* in_sizes, int n_in,
                              void* d_out, int out_size, void* d_ws, size_t ws_size,
                              hipStream_t stream)
{
    const float* x       = (const float*)d_in[0];
    const int*   ei      = (const int*)  d_in[1];
    const float* W       = (const float*)d_in[2];
    const float* att_src = (const float*)d_in[3];
    const float* att_dst = (const float*)d_in[4];
    const float* bias    = (const float*)d_in[5];
    float* out = (float*)d_out;

    const int N  = in_sizes[0] / F_IN;   // 50000
    const int E  = in_sizes[1] / 2;      // 320000
    const int Et = E + N;                // with self loops
    const int NB = (N + 1023) / 1024;    // scan blocks (49)

    // workspace layout
    unsigned short* hb = (unsigned short*)d_ws;                    // N*HC bf16
    float* a_src  = (float*)(hb + (size_t)N * HC);
    float* a_dst  = a_src + (size_t)N * H_HEADS;
    float* denom  = a_dst + (size_t)N * H_HEADS;
    unsigned short* xb = (unsigned short*)(denom + (size_t)N * H_HEADS);
    unsigned short* Wt = xb + (size_t)N * F_IN;
    int* cnt  = (int*)(Wt + (size_t)HC * F_IN);
    int* ex   = cnt + N;
    int* bsum = ex + N;
    int* perm = bsum + 64;

    hipMemsetAsync(d_out, 0, (size_t)out_size * sizeof(float), stream);
    hipMemsetAsync(denom, 0, (size_t)N * H_HEADS * sizeof(float), stream);
    hipMemsetAsync(cnt, 0, (size_t)N * sizeof(int), stream);

    int total4 = N * F_IN / 4;
    cvt_x_kernel<<<(total4 + 255) / 256, 256, 0, stream>>>(x, xb, total4);
    cvt_w_kernel<<<(F_IN * HC + 255) / 256, 256, 0, stream>>>(W, Wt);

    // counting sort by src
    hist_kernel<<<(Et + 255) / 256, 256, 0, stream>>>(ei, cnt, E, Et);
    scan_block_kernel<<<NB, 256, 0, stream>>>(cnt, ex, bsum, N);
    scan_bsum_kernel<<<1, 64, 0, stream>>>(bsum, NB);
    scatter_kernel<<<(Et + 255) / 256, 256, 0, stream>>>(ei, bsum, ex, perm, E, Et);

    dim3 g1((N + 63) / 64, HC / 48);     // 782 x 11
    gemm_att_kernel<<<g1, 256, 0, stream>>>(xb, Wt, att_src, att_dst,
                                            hb, a_src, a_dst, N);

    int totD = Et * H_HEADS;
    denom_kernel<<<(totD + 255) / 256, 256, 0, stream>>>(ei, perm, a_src, a_dst,
                                                         denom, E, Et);

    int totA = N * H_HEADS;
    inv_kernel<<<(totA + 255) / 256, 256, 0, stream>>>(denom, totA);

    aggregate_kernel<<<(Et + EPB - 1) / EPB, 256, 0, stream>>>(
        ei, perm, a_src, a_dst, denom, hb, out, E, Et);

    int totO = N * C_CH;
    finalize_kernel<<<(totO + 255) / 256, 256, 0, stream>>>(out, bias, totO);
}